// Round 3
// baseline (1029.709 us; speedup 1.0000x reference)
//
#include <hip/hip_runtime.h>

// ============================================================================
// PolyAlexNet forward (round 7).
//   Post-mortem r6: SQ_LDS_BANK_CONFLICT bit-identical (7,008,000) across two
//   swizzles -> counter is the structural 2-deep bank serialization of 1KB
//   wave LDS ops (0.013% of cycles, benign). Real signal: VALUBusy 31% >
//   MfmaUtil 27% -> ~156 VALU instr/wave-chunk of per-chunk ADDRESS REBUILD
//   (div/magic-mul, bounds, 64b addr) vs 16 MFMAs.
//   Round-7 change: kill per-chunk address math for conv2..5.
//     - inputs pre-padded in global NHWC (pool1->31x31, pool2->15x15,
//       conv3/4 epilogues write padded 15x15 directly; borders zeroed once).
//       No spatial bounds checks in the K-loop.
//     - C%32==0 -> (r,s) uniform per chunk; per-lane base pointer precomputed,
//       per-chunk offset advanced by a scalar incremental state machine
//       (koff+=32, wrap -> s++/r++). loadB = one uniform-offset vector load.
//     - A loads: clamped base pointers, branchless aptr+kc.
//   conv1 keeps round-6 KRUN path (r varies across g there).
//   FCs / pools / transforms: round-6 structure.
// ============================================================================

typedef _Float16 f16;
typedef _Float16 f16x8 __attribute__((ext_vector_type(8)));
typedef float    f32x4 __attribute__((ext_vector_type(4)));

#define CDIV(a,b) (((a)+(b)-1)/(b))
#define SWZ(row,g) ((g) ^ (((row) >> 2) & 3))

// ---------------------------------------------------------------- conv+poly
// D = A*B: A = weights [OC x K], B = im2col [K x N], N = 64*OH*OW pixels.
// Input is PRE-PADDED: dims HP x WP, filter tap (r,s) reads (oy*STRIDE+r,
// ox*STRIDE+s) with no bounds. OPAD: zero-border padding applied to the
// OUTPUT write location (to feed the next conv without bounds checks).
// KRUN > 0: conv1 path (per-r runs padded to KRUN f16, per-chunk gather).
template<int C,int HP,int WP,int OC,int R,int S,int STRIDE,int OH,int OW,
         int OPAD,int KRUN,int BM,int BN>
__global__ __launch_bounds__(256)
void conv_mfma(const f16* __restrict__ in, const f16* __restrict__ wt,
               const float* __restrict__ bias, f16* __restrict__ out)
{
    constexpr int KTOT = (KRUN > 0) ? (R * KRUN) : (C * R * S);
    constexpr int KP   = (KTOT + 31) & ~31;
    static_assert(KRUN > 0 || KP == KTOT, "padded path requires K % 32 == 0");
    constexpr int OHW  = OH * OW;
    constexpr int NTOT = 64 * OHW;
    constexpr int AM   = BM / 32;          // m-subtiles per wave (wave = BM/2 x BN/2)
    constexpr int AN   = BN / 32;
    constexpr int AU   = BM * 4 / 256;     // 16B staging units per thread (A)
    constexpr int BU   = BN * 4 / 256;     // 16B staging units per thread (B)
    constexpr int HPo  = OH + 2 * OPAD;
    constexpr int WPo  = OW + 2 * OPAD;

    __shared__ __align__(16) f16 As[BM * 32];
    __shared__ __align__(16) f16 Bs[BN * 32];

    const int t   = threadIdx.x;
    const int n0  = blockIdx.x * BN;
    const int oc0 = blockIdx.y * BM;

    // ---- A staging: per-lane base pointers, clamped rows (invalid rows read
    // row 0; their results are discarded in the epilogue)
    int a_lds[AU]; const f16* aptr[AU];
    #pragma unroll
    for (int i = 0; i < AU; ++i) {
        const int u   = t + i * 256;
        const int row = u >> 2;
        const int g   = u & 3;
        a_lds[i] = row * 32 + SWZ(row, g) * 8;
        const int rowc = (oc0 + row < OC) ? (oc0 + row) : 0;
        aptr[i] = wt + (size_t)rowc * KP + g * 8;
    }
    // ---- B staging: pixel decompose once; per-lane base pointer (clamped)
    int b_lds[BU], b_g[BU], b_img[BU], b_oy[BU], b_ox[BU]; bool b_ok[BU];
    const f16* bptr[BU];
    #pragma unroll
    for (int i = 0; i < BU; ++i) {
        const int u   = t + i * 256;
        const int row = u >> 2;
        b_g[i]   = u & 3;
        b_lds[i] = row * 32 + SWZ(row, b_g[i]) * 8;
        const int n   = n0 + row;
        b_ok[i]       = n < NTOT;
        const int ncl = b_ok[i] ? n : 0;
        b_img[i] = ncl / OHW;
        const int rem = ncl - b_img[i] * OHW;
        b_oy[i]  = rem / OW;
        b_ox[i]  = rem - b_oy[i] * OW;
        bptr[i]  = in + ((size_t)(b_img[i] * HP + b_oy[i] * STRIDE) * WP
                         + b_ox[i] * STRIDE) * C + b_g[i] * 8;
    }

    // ---- wave / lane ids
    const int wv = t >> 6;
    const int wm = (wv >> 1) * (BM / 2);
    const int wn = (wv & 1) * (BN / 2);
    const int l  = t & 63;
    const int il = l & 15;
    const int q  = l >> 4;

    f32x4 acc[AM][AN];
    #pragma unroll
    for (int i = 0; i < AM; ++i)
        #pragma unroll
        for (int j = 0; j < AN; ++j)
            acc[i][j] = (f32x4){0.f, 0.f, 0.f, 0.f};

    int4 aReg[AU], bReg[BU];

    auto loadA = [&](int kc) {
        #pragma unroll
        for (int i = 0; i < AU; ++i)
            aReg[i] = *(const int4*)(aptr[i] + kc);
    };
    // padded path: wave-uniform element offset, no bounds
    auto loadBp = [&](int koff) {
        #pragma unroll
        for (int i = 0; i < BU; ++i)
            bReg[i] = *(const int4*)(bptr[i] + koff);
    };
    // conv1 KRUN path (round-6): per-r runs padded to KRUN, pad 0
    auto loadB1 = [&](int kc) {
        if constexpr (KRUN > 0) {
            #pragma unroll
            for (int i = 0; i < BU; ++i) {
                const int k8 = kc + b_g[i] * 8;
                const int r  = k8 / KRUN;
                const int j0 = k8 - r * KRUN;
                int4 v = {0, 0, 0, 0};
                if (b_ok[i] && k8 < KTOT) {
                    const f16* p = in + ((size_t)(b_img[i] * HP + b_oy[i] * STRIDE + r) * WP
                                         + b_ox[i] * STRIDE) * C + j0;
                    const int2 lo = *(const int2*)p;
                    const int2 hi = *(const int2*)(p + 4);
                    v.x = lo.x; v.y = lo.y; v.z = hi.x; v.w = hi.y;
                }
                bReg[i] = v;
            }
        }
    };

    loadA(0);
    if constexpr (KRUN > 0) loadB1(0); else loadBp(0);

    // scalar incremental K-state (wave-uniform): koff = (r*WP + s)*C + cbase
    int ks = 0, kcb = 0, koff = 0;

    for (int kc = 0; kc < KP; kc += 32) {
        // ---- write prefetched chunk to LDS
        #pragma unroll
        for (int i = 0; i < AU; ++i) *(int4*)&As[a_lds[i]] = aReg[i];
        #pragma unroll
        for (int i = 0; i < BU; ++i) *(int4*)&Bs[b_lds[i]] = bReg[i];
        __syncthreads();

        // ---- prefetch next chunk under the MFMAs
        if (kc + 32 < KP) {
            loadA(kc + 32);
            if constexpr (KRUN > 0) {
                loadB1(kc + 32);
            } else {
                koff += 32; kcb += 32;
                if (kcb == C) {
                    kcb = 0;
                    if (++ks == S) { ks = 0; koff += (WP - S) * C; }
                }
                loadBp(koff);
            }
        }

        f16x8 af[AM], bf[AN];
        #pragma unroll
        for (int mi = 0; mi < AM; ++mi) {
            const int row = wm + mi * 16 + il;
            af[mi] = *(const f16x8*)&As[row * 32 + SWZ(row, q) * 8];
        }
        #pragma unroll
        for (int ni = 0; ni < AN; ++ni) {
            const int row = wn + ni * 16 + il;
            bf[ni] = *(const f16x8*)&Bs[row * 32 + SWZ(row, q) * 8];
        }
        #pragma unroll
        for (int mi = 0; mi < AM; ++mi)
            #pragma unroll
            for (int ni = 0; ni < AN; ++ni)
                acc[mi][ni] = __builtin_amdgcn_mfma_f32_16x16x32_f16(
                    af[mi], bf[ni], acc[mi][ni], 0, 0, 0);
        __syncthreads();
    }

    // ---- poly epilogue: out = (acc + bias + 1)^2, NHWC fp16, OPAD-shifted
    size_t noff[AN]; bool nok[AN];
    #pragma unroll
    for (int ni = 0; ni < AN; ++ni) {
        const int nn = n0 + wn + ni * 16 + il;
        nok[ni] = nn < NTOT;
        const int ncl = nok[ni] ? nn : 0;
        const int img = ncl / OHW;
        const int rem = ncl - img * OHW;
        const int oy  = rem / OW;
        const int ox  = rem - oy * OW;
        noff[ni] = ((size_t)(img * HPo + oy + OPAD) * WPo + (ox + OPAD)) * OC;
    }
    #pragma unroll
    for (int mi = 0; mi < AM; ++mi) {
        const int ocb = oc0 + wm + mi * 16 + q * 4;
        if (ocb >= OC) continue;
        const float4 bb = *(const float4*)(bias + ocb);
        const float b4[4] = {bb.x + 1.f, bb.y + 1.f, bb.z + 1.f, bb.w + 1.f};
        #pragma unroll
        for (int ni = 0; ni < AN; ++ni) {
            if (!nok[ni]) continue;
            const f32x4 v = acc[mi][ni];
            union { f16 h[4]; uint2 u; } cv;
            const float vv[4] = {v.x, v.y, v.z, v.w};
            #pragma unroll
            for (int rr = 0; rr < 4; ++rr) {
                const float y = vv[rr] + b4[rr];
                cv.h[rr] = (f16)(y * y);
            }
            *(uint2*)(out + noff[ni] + ocb) = cv.u;
        }
    }
}

// ---------------------------------------------------------------- FC GEMM
// P[s][64][Npad] (fp32) = X[64][k-slab] @ W[k-slab][n-tile]
template<bool TAIL>
__global__ __launch_bounds__(256)
void fc_mfma2(const f16* __restrict__ X, const float* __restrict__ Wm,
              float* __restrict__ P, int N, int Npad, int K, int kchunk)
{
    __shared__ __align__(16) f16 Xs[64 * 32];    // 4 KB
    __shared__ __align__(16) f16 Ws[256 * 32];   // 16 KB

    const int t  = threadIdx.x;
    const int n0 = blockIdx.x * 256;
    const int s  = blockIdx.y;
    const int k0 = s * kchunk;
    const int nIter = kchunk / 32;

    const bool wok = !TAIL || (n0 + t) < N;
    const float* __restrict__ wbase = Wm + (size_t)k0 * N + n0 + t;
    const int xm = t >> 2;
    const int xg = t & 3;
    const f16* __restrict__ xbase = X + (size_t)xm * K + k0 + xg * 8;
    const int xoff = xm * 32 + SWZ(xm, xg) * 8;

    const int wq = t >> 6;
    const int l  = t & 63;
    const int il = l & 15;
    const int q  = l >> 4;

    f32x4 acc[4][4];
    #pragma unroll
    for (int i = 0; i < 4; ++i)
        #pragma unroll
        for (int j = 0; j < 4; ++j)
            acc[i][j] = (f32x4){0.f, 0.f, 0.f, 0.f};

    float wreg[4][8];
    int4  xreg;

    auto loadChunk = [&](int it) {
        const size_t kbase = (size_t)it * 32;
        #pragma unroll
        for (int g = 0; g < 4; ++g)
            #pragma unroll
            for (int j = 0; j < 8; ++j)
                wreg[g][j] = wok ? wbase[(kbase + g * 8 + j) * N] : 0.f;
        xreg = *(const int4*)(xbase + kbase);
    };

    loadChunk(0);

    for (int it = 0; it < nIter; ++it) {
        #pragma unroll
        for (int g = 0; g < 4; ++g) {
            f16x8 h;
            #pragma unroll
            for (int j = 0; j < 8; ++j) h[j] = (f16)wreg[g][j];
            *(f16x8*)&Ws[t * 32 + SWZ(t, g) * 8] = h;
        }
        *(int4*)&Xs[xoff] = xreg;
        __syncthreads();

        if (it + 1 < nIter) loadChunk(it + 1);

        f16x8 af[4], bf[4];
        #pragma unroll
        for (int mi = 0; mi < 4; ++mi) {
            const int m = mi * 16 + il;
            af[mi] = *(const f16x8*)&Xs[m * 32 + SWZ(m, q) * 8];
        }
        #pragma unroll
        for (int ni = 0; ni < 4; ++ni) {
            const int n = wq * 64 + ni * 16 + il;
            bf[ni] = *(const f16x8*)&Ws[n * 32 + SWZ(n, q) * 8];
        }
        #pragma unroll
        for (int mi = 0; mi < 4; ++mi)
            #pragma unroll
            for (int ni = 0; ni < 4; ++ni)
                acc[mi][ni] = __builtin_amdgcn_mfma_f32_16x16x32_f16(
                    af[mi], bf[ni], acc[mi][ni], 0, 0, 0);
        __syncthreads();
    }

    float* __restrict__ pb = P + (size_t)s * 64 * Npad + n0;
    #pragma unroll
    for (int mi = 0; mi < 4; ++mi) {
        const int m = mi * 16 + q * 4;
        #pragma unroll
        for (int ni = 0; ni < 4; ++ni) {
            const int n = wq * 64 + ni * 16 + il;
            const f32x4 v = acc[mi][ni];
            const float vv[4] = {v.x, v.y, v.z, v.w};
            #pragma unroll
            for (int rr = 0; rr < 4; ++rr)
                pb[(size_t)(m + rr) * Npad + n] = vv[rr];
        }
    }
}

// reduce: out[m][n] = bias[n] + sum_s P[s][m][n]
template<bool F16OUT>
__global__ __launch_bounds__(256)
void fc_reduce(const float* __restrict__ P, const float* __restrict__ bias,
               f16* __restrict__ o16, float* __restrict__ o32,
               int N, int Npad, int S)
{
    const int idx = blockIdx.x * 256 + threadIdx.x;
    const int total = 64 * (N / 4);
    if (idx >= total) return;
    const int n4 = (idx % (N / 4)) * 4;
    const int m  = idx / (N / 4);
    float4 a = *(const float4*)(bias + n4);
    const float* __restrict__ p = P + (size_t)m * Npad + n4;
    for (int s = 0; s < S; ++s) {
        const float4 v = *(const float4*)(p + (size_t)s * 64 * Npad);
        a.x += v.x; a.y += v.y; a.z += v.z; a.w += v.w;
    }
    if (F16OUT) {
        union { f16 h[4]; uint2 u; } cv;
        cv.h[0] = (f16)a.x; cv.h[1] = (f16)a.y;
        cv.h[2] = (f16)a.z; cv.h[3] = (f16)a.w;
        *(uint2*)(o16 + (size_t)m * N + n4) = cv.u;
    } else {
        *(float4*)(o32 + (size_t)m * N + n4) = a;
    }
}

// ---------------------------------------------------------------- NHWC avgpool
// 8 channels per thread; writes into an OPAD-padded output buffer
__global__ __launch_bounds__(256)
void avgpool_nhwc8(const f16* __restrict__ in, f16* __restrict__ out,
                   int C8, int C, int H, int W, int OH, int OW,
                   int HPo, int WPo, int opad, int total8)
{
    const int idx = blockIdx.x * 256 + threadIdx.x;
    if (idx >= total8) return;
    const int c8  = (idx % C8) * 8;
    int rest      = idx / C8;
    const int ox  = rest % OW; rest /= OW;
    const int oy  = rest % OH;
    const int b   = rest / OH;
    const f16* __restrict__ p = in + ((size_t)(b * H + oy * 2) * W + ox * 2) * C + c8;
    float s[8] = {0.f, 0.f, 0.f, 0.f, 0.f, 0.f, 0.f, 0.f};
    #pragma unroll
    for (int r = 0; r < 3; ++r)
        #pragma unroll
        for (int cc = 0; cc < 3; ++cc) {
            const f16x8 v = *(const f16x8*)&p[(r * W + cc) * C];
            #pragma unroll
            for (int j = 0; j < 8; ++j) s[j] += (float)v[j];
        }
    f16x8 o8;
    #pragma unroll
    for (int j = 0; j < 8; ++j) o8[j] = (f16)(s[j] * (1.f / 9.f));
    *(f16x8*)(out + ((size_t)(b * HPo + oy + opad) * WPo + (ox + opad)) * C + c8) = o8;
}

// zero the pad border of a [64][HPb][WPb][C] NHWC buffer (interior untouched)
__global__ __launch_bounds__(256)
void border_zero(f16* __restrict__ buf, int HPb, int WPb, int C8, int pad,
                 int total8)
{
    const int idx = blockIdx.x * 256 + threadIdx.x;
    if (idx >= total8) return;
    int rest = idx / C8;
    const int x = rest % WPb; rest /= WPb;
    const int y = rest % HPb;
    if (y >= pad && y < HPb - pad && x >= pad && x < WPb - pad) return;
    const int4 z = {0, 0, 0, 0};
    *(int4*)(buf + (size_t)idx * 8) = z;
}

// pool5: NHWC fp16 [64][13][13][256] -> fp16 [64][9216] NCHW-flat
__global__ __launch_bounds__(256)
void pool5_ncflat(const f16* __restrict__ in, f16* __restrict__ out)
{
    const int idx = blockIdx.x * 256 + threadIdx.x;
    if (idx >= 64 * 6 * 6 * 256) return;
    const int c  = idx & 255;
    int rest     = idx >> 8;
    const int ox = rest % 6; rest /= 6;
    const int oy = rest % 6;
    const int b  = rest / 6;
    const f16* __restrict__ p = in + ((size_t)(b * 13 + oy * 2) * 13 + ox * 2) * 256 + c;
    float s = 0.f;
    #pragma unroll
    for (int r = 0; r < 3; ++r)
        #pragma unroll
        for (int cc = 0; cc < 3; ++cc)
            s += (float)p[(r * 13 + cc) * 256];
    out[(size_t)b * 9216 + c * 36 + oy * 6 + ox] = (f16)(s * (1.f / 9.f));
}

// ---------------------------------------------------------------- transforms
// input NCHW fp32 -> NHWC fp16, channels padded 3 -> 4 (pixel = 8B aligned)
__global__ __launch_bounds__(256)
void x_to_nhwc4(const float* __restrict__ x, f16* __restrict__ o)
{
    const int idx = blockIdx.x * 256 + threadIdx.x;
    if (idx >= 64 * 227 * 227) return;
    const int hw = idx % (227 * 227);
    const int b  = idx / (227 * 227);
    const size_t plane = 227 * 227;
    const float* __restrict__ p = x + (size_t)b * 3 * plane + hw;
    union { f16 h[4]; int2 v; } u;
    u.h[0] = (f16)p[0];
    u.h[1] = (f16)p[plane];
    u.h[2] = (f16)p[2 * plane];
    u.h[3] = (f16)0.f;
    *(int2*)(o + (size_t)idx * 4) = u.v;
}

// conv1 weights OIHW fp32 -> [96][r*48 + s*4 + c] fp16, zero-padded (KP=544)
__global__ __launch_bounds__(256)
void wt_tf1(const float* __restrict__ w, f16* __restrict__ o)
{
    const int idx = blockIdx.x * 256 + threadIdx.x;
    if (idx >= 96 * 544) return;
    const int k  = idx % 544;
    const int oc = idx / 544;
    f16 v = (f16)0.f;
    if (k < 528) {
        const int r   = k / 48;
        const int rem = k - r * 48;
        const int s   = rem >> 2;
        const int c   = rem & 3;
        if (s < 11 && c < 3)
            v = (f16)w[(((size_t)oc * 3 + c) * 11 + r) * 11 + s];
    }
    o[idx] = v;
}

// weights OIHW fp32 -> [OC][(r*S+s)*C + c] fp16, K zero-padded to KP
__global__ __launch_bounds__(256)
void wt_tf(const float* __restrict__ w, f16* __restrict__ o,
           int OC, int Cc, int R, int S, int KP)
{
    const int idx = blockIdx.x * 256 + threadIdx.x;
    if (idx >= OC * KP) return;
    const int k  = idx % KP;
    const int oc = idx / KP;
    f16 v = (f16)0.f;
    if (k < Cc * R * S) {
        const int rs = k / Cc;
        const int c  = k - rs * Cc;
        const int r  = rs / S;
        const int s  = rs - r * S;
        v = (f16)w[(((size_t)oc * Cc + c) * R + r) * S + s];
    }
    o[idx] = v;
}

// ============================================================================
extern "C" void kernel_launch(void* const* d_in, const int* in_sizes, int n_in,
                              void* d_out, int out_size, void* d_ws, size_t ws_size,
                              hipStream_t stream)
{
    const float* x   = (const float*)d_in[0];
    const float* w1  = (const float*)d_in[1];
    const float* b1  = (const float*)d_in[2];
    const float* w2  = (const float*)d_in[3];
    const float* b2  = (const float*)d_in[4];
    const float* w3  = (const float*)d_in[5];
    const float* b3  = (const float*)d_in[6];
    const float* w4  = (const float*)d_in[7];
    const float* b4  = (const float*)d_in[8];
    const float* w5  = (const float*)d_in[9];
    const float* b5  = (const float*)d_in[10];
    const float* fw1 = (const float*)d_in[11];
    const float* fb1 = (const float*)d_in[12];
    const float* fw2 = (const float*)d_in[13];
    const float* fb2 = (const float*)d_in[14];
    const float* fw3 = (const float*)d_in[15];
    const float* fb3 = (const float*)d_in[16];
    float* out = (float*)d_out;

    char* ws = (char*)d_ws;
    const size_t MiB = 1024 * 1024;

    // ws map (MiB offsets; lifetimes disjoint where regions overlap):
    //   [0,  7.2)  Wt   packed conv weights      (transforms .. conv5)
    //   [8,  10)   Xh1  [64][9216] f16           (pool5 .. fc1)
    //   [10, 11)   Xh2; [11,12) Xh3              (FC stage)
    //   [12, 37.2) X0   conv1 input              (x_to_nhwc4 .. conv1)
    //   [12, 34.8) A2   conv2 out 27x27x256      (conv2 .. pool2)   [X0 dead]
    //   [12, 28)   P    FC partials              (FC stage)         [A2 dead]
    //   [35, 42.1) Bp3  padded 15x15x256         (bzero .. conv3)
    //   [43, 78.5) A1   conv1 out 55x55x96       (conv1 .. pool1)
    //   [43, 53.6) A4   padded 15x15x384         (bzero* .. conv4)  [A1 dead]
    //   [54, 64.6) Bp5  padded 15x15x384         (bzero* .. conv5)  [A1 dead]
    //   [65, 70.3) A5   conv5 out 13x13x256      (conv5 .. pool5)   [A1 dead]
    //   [79, 90.3) Bp2  padded 31x31x96          (bzero .. conv2)
    //   (* bzero for A4/Bp5/Bp3 runs after pool1, when A1 is dead)
    f16*   Wt1 = (f16*)(ws);
    f16*   Wt2 = Wt1 + (size_t)96  * 544;
    f16*   Wt3 = Wt2 + (size_t)256 * 2400;
    f16*   Wt4 = Wt3 + (size_t)384 * 2304;
    f16*   Wt5 = Wt4 + (size_t)384 * 3456;
    f16*   Xh1 = (f16*)(ws + 8  * MiB);
    f16*   Xh2 = (f16*)(ws + 10 * MiB);
    f16*   Xh3 = (f16*)(ws + 11 * MiB);
    f16*   X0  = (f16*)(ws + 12 * MiB);
    f16*   A2  = (f16*)(ws + 12 * MiB);
    float* P   = (float*)(ws + 12 * MiB);
    f16*   Bp3 = (f16*)(ws + 35 * MiB);
    f16*   A1  = (f16*)(ws + 43 * MiB);
    f16*   A4  = (f16*)(ws + 43 * MiB);
    f16*   Bp5 = (f16*)(ws + 54 * MiB);
    f16*   A5  = (f16*)(ws + 65 * MiB);
    f16*   Bp2 = (f16*)(ws + 79 * MiB);

    // ---- conv weight transforms (tiny)
    wt_tf1<<<CDIV(96 * 544, 256), 256, 0, stream>>>(w1, Wt1);
    wt_tf<<<CDIV(256 * 2400, 256), 256, 0, stream>>>(w2, Wt2, 256, 96 , 5, 5, 2400);
    wt_tf<<<CDIV(384 * 2304, 256), 256, 0, stream>>>(w3, Wt3, 384, 256, 3, 3, 2304);
    wt_tf<<<CDIV(384 * 3456, 256), 256, 0, stream>>>(w4, Wt4, 384, 384, 3, 3, 3456);
    wt_tf<<<CDIV(256 * 3456, 256), 256, 0, stream>>>(w5, Wt5, 256, 384, 3, 3, 3456);

    // ---- input to NHWC fp16, C padded to 4; zero Bp2 border (disjoint from A1)
    x_to_nhwc4<<<CDIV(64 * 227 * 227, 256), 256, 0, stream>>>(x, X0);
    border_zero<<<CDIV(64 * 31 * 31 * 12, 256), 256, 0, stream>>>(Bp2, 31, 31, 12, 2, 64 * 31 * 31 * 12);

    // conv1: [64,227,227,4] -> [64,55,55,96]  (KRUN=48, K=528, KP=544)
    conv_mfma<4,227,227,96,11,11,4,55,55,0,48,128,128>
        <<<dim3(CDIV(64 * 55 * 55, 128), 1), 256, 0, stream>>>(X0, Wt1, b1, A1);
    // pool1 -> padded [64][31][31][96]
    avgpool_nhwc8<<<CDIV(64 * 27 * 27 * 12, 256), 256, 0, stream>>>(
        A1, Bp2, 12, 96, 55, 55, 27, 27, 31, 31, 2, 64 * 27 * 27 * 12);

    // A1 now dead: zero borders of Bp3 / A4 / Bp5
    border_zero<<<CDIV(64 * 15 * 15 * 32, 256), 256, 0, stream>>>(Bp3, 15, 15, 32, 1, 64 * 15 * 15 * 32);
    border_zero<<<CDIV(64 * 15 * 15 * 48, 256), 256, 0, stream>>>(A4 , 15, 15, 48, 1, 64 * 15 * 15 * 48);
    border_zero<<<CDIV(64 * 15 * 15 * 48, 256), 256, 0, stream>>>(Bp5, 15, 15, 48, 1, 64 * 15 * 15 * 48);

    // conv2: padded [64,31,31,96] -> dense [64,27,27,256]
    conv_mfma<96,31,31,256,5,5,1,27,27,0,0,128,128>
        <<<dim3(CDIV(64 * 27 * 27, 128), 2), 256, 0, stream>>>(Bp2, Wt2, b2, A2);
    // pool2 -> padded [64][15][15][256]
    avgpool_nhwc8<<<CDIV(64 * 13 * 13 * 32, 256), 256, 0, stream>>>(
        A2, Bp3, 32, 256, 27, 27, 13, 13, 15, 15, 1, 64 * 13 * 13 * 32);

    // conv3..5: N=10816 -> 169 n-blocks exactly (no tail)
    conv_mfma<256,15,15,384,3,3,1,13,13,1,0,128,64>
        <<<dim3(169, 3), 256, 0, stream>>>(Bp3, Wt3, b3, A4);
    conv_mfma<384,15,15,384,3,3,1,13,13,1,0,128,64>
        <<<dim3(169, 3), 256, 0, stream>>>(A4, Wt4, b4, Bp5);
    conv_mfma<384,15,15,256,3,3,1,13,13,0,0,128,64>
        <<<dim3(169, 2), 256, 0, stream>>>(Bp5, Wt5, b5, A5);

    // pool5 -> Xh1 [64][9216] f16
    pool5_ncflat<<<CDIV(64 * 6 * 6 * 256, 256), 256, 0, stream>>>(A5, Xh1);

    // ---- FC stack: split-K partials + reduce (no atomics)
    fc_mfma2<false><<<dim3(16, 16), 256, 0, stream>>>(Xh1, fw1, P, 4096, 4096, 9216, 576);
    fc_reduce<true><<<CDIV(64 * 4096 / 4, 256), 256, 0, stream>>>(P, fb1, Xh2, nullptr, 4096, 4096, 16);
    fc_mfma2<false><<<dim3(16, 16), 256, 0, stream>>>(Xh2, fw2, P, 4096, 4096, 4096, 256);
    fc_reduce<true><<<CDIV(64 * 4096 / 4, 256), 256, 0, stream>>>(P, fb2, Xh3, nullptr, 4096, 4096, 16);
    fc_mfma2<true><<<dim3(4, 64), 256, 0, stream>>>(Xh3, fw3, P, 1000, 1024, 4096, 64);
    fc_reduce<false><<<CDIV(64 * 1000 / 4, 256), 256, 0, stream>>>(P, fb3, nullptr, out, 1000, 1024, 64);
}

// Round 4
// 682.183 us; speedup vs baseline: 1.5094x; 1.5094x over previous
//
#include <hip/hip_runtime.h>

// ============================================================================
// PolyAlexNet forward (round 8).
//   Post-mortem r7: padded-buffer + uniform-offset rewrite DID kill VALU
//   (31%->3.4%) but exploded HBM traffic (WRITE 32->456 MB, 19x output;
//   unexplained) -> conv2 88.6 -> 276.6 us. REVERTED to round-6 memory
//   behavior wholesale: dense buffers, identical grids, identical load/store
//   address streams, exec-masked boundary skips.
//   Round-8 change (VALU only): C%32==0 -> the (r,s) filter tap is constant
//   across C/32 consecutive k-chunks. Hoist iy/ix/valid/pointer computation
//   to once per (r,s) (scalar incremental r,s wrap - no divisions); per chunk
//   the B-load is just an exec-masked load at (bcur + ccoff), ccoff += 32.
//   Same loads, same skips, same addresses - only ~5x less address VALU.
//   conv1 keeps round-6 KRUN gather path. FCs/pools/transforms: round-6.
// ============================================================================

typedef _Float16 f16;
typedef _Float16 f16x8 __attribute__((ext_vector_type(8)));
typedef float    f32x4 __attribute__((ext_vector_type(4)));

#define CDIV(a,b) (((a)+(b)-1)/(b))
// LDS swizzle: 16B unit g of row stored at slot g ^ ((row>>2)&3)
#define SWZ(row,g) ((g) ^ (((row) >> 2) & 3))

// ---------------------------------------------------------------- conv+poly
// D = A*B: A = weights [OC x K], B = im2col [K x N], N = 64*OH*OW pixels.
// mfma_f32_16x16x32_f16: A/B-frag row = lane&15, k = (lane>>4)*8+j
//                        C/D col(n) = lane&15, row(m) = (lane>>4)*4+reg
// KRUN == 0: vector path, C % 32 == 0 (a chunk has fixed (r,s)).
// KRUN  > 0: conv1 path, per-r run padded to KRUN f16; C = padded channels.
template<int C,int H,int W,int OC,int R,int S,int PAD,int STRIDE,int OH,int OW,
         int KRUN,int BM,int BN>
__global__ __launch_bounds__(256)
void conv_mfma(const f16* __restrict__ in, const f16* __restrict__ wt,
               const float* __restrict__ bias, f16* __restrict__ out)
{
    constexpr int KTOT = (KRUN > 0) ? (R * KRUN) : (C * R * S);
    constexpr int KP   = (KTOT + 31) & ~31;
    static_assert(KRUN > 0 || (C % 32) == 0, "vector path requires C % 32 == 0");
    constexpr int OHW  = OH * OW;
    constexpr int NTOT = 64 * OHW;
    constexpr int AM   = BM / 32;          // m-subtiles per wave (wave = BM/2 x BN/2)
    constexpr int AN   = BN / 32;
    constexpr int AU   = BM * 4 / 256;     // 16B staging units per thread (A)
    constexpr int BU   = BN * 4 / 256;     // 16B staging units per thread (B)

    __shared__ __align__(16) f16 As[BM * 32];
    __shared__ __align__(16) f16 Bs[BN * 32];

    const int t   = threadIdx.x;
    const int n0  = blockIdx.x * BN;
    const int oc0 = blockIdx.y * BM;

    // ---- A staging metadata (round-6: masked loads; clamped pointer base)
    int a_lds[AU]; bool a_ok[AU]; const f16* aptr[AU];
    #pragma unroll
    for (int i = 0; i < AU; ++i) {
        const int u   = t + i * 256;
        const int row = u >> 2;
        const int g   = u & 3;
        a_lds[i] = row * 32 + SWZ(row, g) * 8;
        a_ok[i]  = (oc0 + row) < OC;
        const int rowc = a_ok[i] ? (oc0 + row) : 0;
        aptr[i] = wt + (size_t)rowc * KP + g * 8;
    }
    // ---- B staging metadata (pixel decompose once)
    int b_lds[BU], b_g[BU], b_img[BU], b_oy[BU], b_ox[BU]; bool b_ok[BU];
    #pragma unroll
    for (int i = 0; i < BU; ++i) {
        const int u   = t + i * 256;
        const int row = u >> 2;
        b_g[i]   = u & 3;
        b_lds[i] = row * 32 + SWZ(row, b_g[i]) * 8;
        const int n   = n0 + row;
        b_ok[i]       = n < NTOT;
        const int ncl = b_ok[i] ? n : 0;
        b_img[i] = ncl / OHW;
        const int rem = ncl - b_img[i] * OHW;
        b_oy[i]  = rem / OW;
        b_ox[i]  = rem - b_oy[i] * OW;
    }

    // ---- wave / lane ids
    const int wv = t >> 6;
    const int wm = (wv >> 1) * (BM / 2);
    const int wn = (wv & 1) * (BN / 2);
    const int l  = t & 63;
    const int il = l & 15;
    const int q  = l >> 4;

    f32x4 acc[AM][AN];
    #pragma unroll
    for (int i = 0; i < AM; ++i)
        #pragma unroll
        for (int j = 0; j < AN; ++j)
            acc[i][j] = (f32x4){0.f, 0.f, 0.f, 0.f};

    int4 aReg[AU], bReg[BU];

    auto loadA = [&](int kc) {
        #pragma unroll
        for (int i = 0; i < AU; ++i) {
            int4 v = {0, 0, 0, 0};
            if (a_ok[i]) v = *(const int4*)(aptr[i] + kc);
            aReg[i] = v;
        }
    };

    // ---- vector path: per-(r,s) hoisted state. Same addresses / same skips
    // as round 6; only the per-chunk recompute is gone.
    const f16* bcur[BU]; bool bval[BU];
    auto setRS = [&](int r, int s) {
        if constexpr (KRUN == 0) {
            #pragma unroll
            for (int i = 0; i < BU; ++i) {
                const int iy = b_oy[i] * STRIDE + r - PAD;
                const int ix = b_ox[i] * STRIDE + s - PAD;
                bval[i] = b_ok[i] && iy >= 0 && iy < H && ix >= 0 && ix < W;
                bcur[i] = in + ((size_t)(b_img[i] * H + iy) * W + ix) * C + b_g[i] * 8;
            }
        }
    };
    auto loadBv = [&](int ccoff) {
        #pragma unroll
        for (int i = 0; i < BU; ++i) {
            int4 v = {0, 0, 0, 0};
            if (bval[i]) v = *(const int4*)(bcur[i] + ccoff);
            bReg[i] = v;
        }
    };
    // ---- conv1 KRUN path (round-6): per-r runs padded to KRUN, pad 0
    auto loadB1 = [&](int kc) {
        if constexpr (KRUN > 0) {
            #pragma unroll
            for (int i = 0; i < BU; ++i) {
                const int k8 = kc + b_g[i] * 8;
                const int r  = k8 / KRUN;
                const int j0 = k8 - r * KRUN;
                int4 v = {0, 0, 0, 0};
                if (b_ok[i] && k8 < KTOT) {
                    const f16* p = in + ((size_t)(b_img[i] * H + b_oy[i] * STRIDE + r) * W
                                         + b_ox[i] * STRIDE) * C + j0;
                    const int2 lo = *(const int2*)p;
                    const int2 hi = *(const int2*)(p + 4);
                    v.x = lo.x; v.y = lo.y; v.z = hi.x; v.w = hi.y;
                }
                bReg[i] = v;
            }
        }
    };

    loadA(0);
    if constexpr (KRUN > 0) { loadB1(0); }
    else                    { setRS(0, 0); loadBv(0); }

    int rn = 0, sn = 0, ccn = 0;   // wave-uniform next-chunk tap state

    for (int kc = 0; kc < KP; kc += 32) {
        // ---- write prefetched chunk to LDS
        #pragma unroll
        for (int i = 0; i < AU; ++i) *(int4*)&As[a_lds[i]] = aReg[i];
        #pragma unroll
        for (int i = 0; i < BU; ++i) *(int4*)&Bs[b_lds[i]] = bReg[i];
        __syncthreads();

        // ---- prefetch next chunk under the MFMAs
        if (kc + 32 < KP) {
            loadA(kc + 32);
            if constexpr (KRUN > 0) {
                loadB1(kc + 32);
            } else {
                ccn += 32;
                if (ccn == C) {
                    ccn = 0;
                    if (++sn == S) { sn = 0; ++rn; }
                    setRS(rn, sn);
                }
                loadBv(ccn);
            }
        }

        f16x8 af[AM], bf[AN];
        #pragma unroll
        for (int mi = 0; mi < AM; ++mi) {
            const int row = wm + mi * 16 + il;
            af[mi] = *(const f16x8*)&As[row * 32 + SWZ(row, q) * 8];
        }
        #pragma unroll
        for (int ni = 0; ni < AN; ++ni) {
            const int row = wn + ni * 16 + il;
            bf[ni] = *(const f16x8*)&Bs[row * 32 + SWZ(row, q) * 8];
        }
        #pragma unroll
        for (int mi = 0; mi < AM; ++mi)
            #pragma unroll
            for (int ni = 0; ni < AN; ++ni)
                acc[mi][ni] = __builtin_amdgcn_mfma_f32_16x16x32_f16(
                    af[mi], bf[ni], acc[mi][ni], 0, 0, 0);
        __syncthreads();
    }

    // ---- poly epilogue: out[n][oc] = (acc + bias[oc] + 1)^2, NHWC fp16
    #pragma unroll
    for (int mi = 0; mi < AM; ++mi) {
        const int ocb = oc0 + wm + mi * 16 + q * 4;
        if (ocb >= OC) continue;
        const float4 bb = *(const float4*)(bias + ocb);
        const float b4[4] = {bb.x + 1.f, bb.y + 1.f, bb.z + 1.f, bb.w + 1.f};
        #pragma unroll
        for (int ni = 0; ni < AN; ++ni) {
            const int nn = n0 + wn + ni * 16 + il;
            if (nn >= NTOT) continue;
            const f32x4 v = acc[mi][ni];
            union { f16 h[4]; uint2 u; } cv;
            const float vv[4] = {v.x, v.y, v.z, v.w};
            #pragma unroll
            for (int rr = 0; rr < 4; ++rr) {
                const float y = vv[rr] + b4[rr];
                cv.h[rr] = (f16)(y * y);
            }
            *(uint2*)(out + (size_t)nn * OC + ocb) = cv.u;
        }
    }
}

// ---------------------------------------------------------------- FC GEMM
// P[s][64][Npad] (fp32) = X[64][k-slab] @ W[k-slab][n-tile]
template<bool TAIL>
__global__ __launch_bounds__(256)
void fc_mfma2(const f16* __restrict__ X, const float* __restrict__ Wm,
              float* __restrict__ P, int N, int Npad, int K, int kchunk)
{
    __shared__ __align__(16) f16 Xs[64 * 32];    // 4 KB
    __shared__ __align__(16) f16 Ws[256 * 32];   // 16 KB

    const int t  = threadIdx.x;
    const int n0 = blockIdx.x * 256;
    const int s  = blockIdx.y;
    const int k0 = s * kchunk;
    const int nIter = kchunk / 32;

    const bool wok = !TAIL || (n0 + t) < N;
    const float* __restrict__ wbase = Wm + (size_t)k0 * N + n0 + t;
    const int xm = t >> 2;
    const int xg = t & 3;
    const f16* __restrict__ xbase = X + (size_t)xm * K + k0 + xg * 8;
    const int xoff = xm * 32 + SWZ(xm, xg) * 8;

    const int wq = t >> 6;
    const int l  = t & 63;
    const int il = l & 15;
    const int q  = l >> 4;

    f32x4 acc[4][4];
    #pragma unroll
    for (int i = 0; i < 4; ++i)
        #pragma unroll
        for (int j = 0; j < 4; ++j)
            acc[i][j] = (f32x4){0.f, 0.f, 0.f, 0.f};

    float wreg[4][8];
    int4  xreg;

    auto loadChunk = [&](int it) {
        const size_t kbase = (size_t)it * 32;
        #pragma unroll
        for (int g = 0; g < 4; ++g)
            #pragma unroll
            for (int j = 0; j < 8; ++j)
                wreg[g][j] = wok ? wbase[(kbase + g * 8 + j) * N] : 0.f;
        xreg = *(const int4*)(xbase + kbase);
    };

    loadChunk(0);

    for (int it = 0; it < nIter; ++it) {
        #pragma unroll
        for (int g = 0; g < 4; ++g) {
            f16x8 h;
            #pragma unroll
            for (int j = 0; j < 8; ++j) h[j] = (f16)wreg[g][j];
            *(f16x8*)&Ws[t * 32 + SWZ(t, g) * 8] = h;
        }
        *(int4*)&Xs[xoff] = xreg;
        __syncthreads();

        if (it + 1 < nIter) loadChunk(it + 1);

        f16x8 af[4], bf[4];
        #pragma unroll
        for (int mi = 0; mi < 4; ++mi) {
            const int m = mi * 16 + il;
            af[mi] = *(const f16x8*)&Xs[m * 32 + SWZ(m, q) * 8];
        }
        #pragma unroll
        for (int ni = 0; ni < 4; ++ni) {
            const int n = wq * 64 + ni * 16 + il;
            bf[ni] = *(const f16x8*)&Ws[n * 32 + SWZ(n, q) * 8];
        }
        #pragma unroll
        for (int mi = 0; mi < 4; ++mi)
            #pragma unroll
            for (int ni = 0; ni < 4; ++ni)
                acc[mi][ni] = __builtin_amdgcn_mfma_f32_16x16x32_f16(
                    af[mi], bf[ni], acc[mi][ni], 0, 0, 0);
        __syncthreads();
    }

    float* __restrict__ pb = P + (size_t)s * 64 * Npad + n0;
    #pragma unroll
    for (int mi = 0; mi < 4; ++mi) {
        const int m = mi * 16 + q * 4;
        #pragma unroll
        for (int ni = 0; ni < 4; ++ni) {
            const int n = wq * 64 + ni * 16 + il;
            const f32x4 v = acc[mi][ni];
            const float vv[4] = {v.x, v.y, v.z, v.w};
            #pragma unroll
            for (int rr = 0; rr < 4; ++rr)
                pb[(size_t)(m + rr) * Npad + n] = vv[rr];
        }
    }
}

// reduce: out[m][n] = bias[n] + sum_s P[s][m][n]
template<bool F16OUT>
__global__ __launch_bounds__(256)
void fc_reduce(const float* __restrict__ P, const float* __restrict__ bias,
               f16* __restrict__ o16, float* __restrict__ o32,
               int N, int Npad, int S)
{
    const int idx = blockIdx.x * 256 + threadIdx.x;
    const int total = 64 * (N / 4);
    if (idx >= total) return;
    const int n4 = (idx % (N / 4)) * 4;
    const int m  = idx / (N / 4);
    float4 a = *(const float4*)(bias + n4);
    const float* __restrict__ p = P + (size_t)m * Npad + n4;
    for (int s = 0; s < S; ++s) {
        const float4 v = *(const float4*)(p + (size_t)s * 64 * Npad);
        a.x += v.x; a.y += v.y; a.z += v.z; a.w += v.w;
    }
    if (F16OUT) {
        union { f16 h[4]; uint2 u; } cv;
        cv.h[0] = (f16)a.x; cv.h[1] = (f16)a.y;
        cv.h[2] = (f16)a.z; cv.h[3] = (f16)a.w;
        *(uint2*)(o16 + (size_t)m * N + n4) = cv.u;
    } else {
        *(float4*)(o32 + (size_t)m * N + n4) = a;
    }
}

// ---------------------------------------------------------------- NHWC avgpool
// 8 channels per thread (16B/lane loads+stores)
__global__ __launch_bounds__(256)
void avgpool_nhwc8(const f16* __restrict__ in, f16* __restrict__ out,
                   int C8, int C, int H, int W, int OH, int OW, int total8)
{
    const int idx = blockIdx.x * 256 + threadIdx.x;
    if (idx >= total8) return;
    const int c8  = (idx % C8) * 8;
    int rest      = idx / C8;
    const int ox  = rest % OW; rest /= OW;
    const int oy  = rest % OH;
    const int b   = rest / OH;
    const f16* __restrict__ p = in + ((size_t)(b * H + oy * 2) * W + ox * 2) * C + c8;
    float s[8] = {0.f, 0.f, 0.f, 0.f, 0.f, 0.f, 0.f, 0.f};
    #pragma unroll
    for (int r = 0; r < 3; ++r)
        #pragma unroll
        for (int cc = 0; cc < 3; ++cc) {
            const f16x8 v = *(const f16x8*)&p[(r * W + cc) * C];
            #pragma unroll
            for (int j = 0; j < 8; ++j) s[j] += (float)v[j];
        }
    f16x8 o8;
    #pragma unroll
    for (int j = 0; j < 8; ++j) o8[j] = (f16)(s[j] * (1.f / 9.f));
    *(f16x8*)(out + (size_t)idx * 8) = o8;
}

// pool5: NHWC fp16 [64][13][13][256] -> fp16 [64][9216] NCHW-flat
__global__ __launch_bounds__(256)
void pool5_ncflat(const f16* __restrict__ in, f16* __restrict__ out)
{
    const int idx = blockIdx.x * 256 + threadIdx.x;
    if (idx >= 64 * 6 * 6 * 256) return;
    const int c  = idx & 255;
    int rest     = idx >> 8;
    const int ox = rest % 6; rest /= 6;
    const int oy = rest % 6;
    const int b  = rest / 6;
    const f16* __restrict__ p = in + ((size_t)(b * 13 + oy * 2) * 13 + ox * 2) * 256 + c;
    float s = 0.f;
    #pragma unroll
    for (int r = 0; r < 3; ++r)
        #pragma unroll
        for (int cc = 0; cc < 3; ++cc)
            s += (float)p[(r * 13 + cc) * 256];
    out[(size_t)b * 9216 + c * 36 + oy * 6 + ox] = (f16)(s * (1.f / 9.f));
}

// ---------------------------------------------------------------- transforms
// input NCHW fp32 -> NHWC fp16, channels padded 3 -> 4 (pixel = 8B aligned)
__global__ __launch_bounds__(256)
void x_to_nhwc4(const float* __restrict__ x, f16* __restrict__ o)
{
    const int idx = blockIdx.x * 256 + threadIdx.x;
    if (idx >= 64 * 227 * 227) return;
    const int hw = idx % (227 * 227);
    const int b  = idx / (227 * 227);
    const size_t plane = 227 * 227;
    const float* __restrict__ p = x + (size_t)b * 3 * plane + hw;
    union { f16 h[4]; int2 v; } u;
    u.h[0] = (f16)p[0];
    u.h[1] = (f16)p[plane];
    u.h[2] = (f16)p[2 * plane];
    u.h[3] = (f16)0.f;
    *(int2*)(o + (size_t)idx * 4) = u.v;
}

// conv1 weights OIHW fp32 -> [96][r*48 + s*4 + c] fp16, zero-padded (KP=544)
__global__ __launch_bounds__(256)
void wt_tf1(const float* __restrict__ w, f16* __restrict__ o)
{
    const int idx = blockIdx.x * 256 + threadIdx.x;
    if (idx >= 96 * 544) return;
    const int k  = idx % 544;
    const int oc = idx / 544;
    f16 v = (f16)0.f;
    if (k < 528) {
        const int r   = k / 48;
        const int rem = k - r * 48;
        const int s   = rem >> 2;
        const int c   = rem & 3;
        if (s < 11 && c < 3)
            v = (f16)w[(((size_t)oc * 3 + c) * 11 + r) * 11 + s];
    }
    o[idx] = v;
}

// weights OIHW fp32 -> [OC][(r*S+s)*C + c] fp16, K zero-padded to KP
__global__ __launch_bounds__(256)
void wt_tf(const float* __restrict__ w, f16* __restrict__ o,
           int OC, int Cc, int R, int S, int KP)
{
    const int idx = blockIdx.x * 256 + threadIdx.x;
    if (idx >= OC * KP) return;
    const int k  = idx % KP;
    const int oc = idx / KP;
    f16 v = (f16)0.f;
    if (k < Cc * R * S) {
        const int rs = k / Cc;
        const int c  = k - rs * Cc;
        const int r  = rs / S;
        const int s  = rs - r * S;
        v = (f16)w[(((size_t)oc * Cc + c) * R + r) * S + s];
    }
    o[idx] = v;
}

// ============================================================================
extern "C" void kernel_launch(void* const* d_in, const int* in_sizes, int n_in,
                              void* d_out, int out_size, void* d_ws, size_t ws_size,
                              hipStream_t stream)
{
    const float* x   = (const float*)d_in[0];
    const float* w1  = (const float*)d_in[1];
    const float* b1  = (const float*)d_in[2];
    const float* w2  = (const float*)d_in[3];
    const float* b2  = (const float*)d_in[4];
    const float* w3  = (const float*)d_in[5];
    const float* b3  = (const float*)d_in[6];
    const float* w4  = (const float*)d_in[7];
    const float* b4  = (const float*)d_in[8];
    const float* w5  = (const float*)d_in[9];
    const float* b5  = (const float*)d_in[10];
    const float* fw1 = (const float*)d_in[11];
    const float* fb1 = (const float*)d_in[12];
    const float* fw2 = (const float*)d_in[13];
    const float* fb2 = (const float*)d_in[14];
    const float* fw3 = (const float*)d_in[15];
    const float* fb3 = (const float*)d_in[16];
    float* out = (float*)d_out;

    char* ws = (char*)d_ws;
    const size_t MiB = 1024 * 1024;

    // ws map (round-6, verified):
    //   [0, 26MiB)    X0 (conv1 input, C4-padded NHWC, 25.2MB; dead after conv1)
    //   [0, 17MiB)    P  (FC partials, <=16.8MB; FC stage only -> overlaps X0)
    //   [17, 21MiB)   Xh1/Xh2/Xh3
    //   [26, 62MiB)   A  (<=37.2MB)
    //   [62, 72MiB)   Bp (<=9.0MB)
    //   [72, 80MiB)   packed conv weights (~7.5MB)
    f16*   X0  = (f16*)(ws);
    float* P   = (float*)(ws);
    f16*   Xh1 = (f16*)(ws + 17 * MiB);
    f16*   Xh2 = (f16*)(ws + 19 * MiB);
    f16*   Xh3 = (f16*)(ws + 20 * MiB);
    f16*   A   = (f16*)(ws + 26 * MiB);
    f16*   Bp  = (f16*)(ws + 62 * MiB);
    f16*   Wt1 = (f16*)(ws + 72 * MiB);
    f16*   Wt2 = Wt1 + (size_t)96  * 544;
    f16*   Wt3 = Wt2 + (size_t)256 * 2400;
    f16*   Wt4 = Wt3 + (size_t)384 * 2304;
    f16*   Wt5 = Wt4 + (size_t)384 * 3456;

    // ---- conv weight transforms (tiny)
    wt_tf1<<<CDIV(96 * 544, 256), 256, 0, stream>>>(w1, Wt1);
    wt_tf<<<CDIV(256 * 2400, 256), 256, 0, stream>>>(w2, Wt2, 256, 96 , 5, 5, 2400);
    wt_tf<<<CDIV(384 * 2304, 256), 256, 0, stream>>>(w3, Wt3, 384, 256, 3, 3, 2304);
    wt_tf<<<CDIV(384 * 3456, 256), 256, 0, stream>>>(w4, Wt4, 384, 384, 3, 3, 3456);
    wt_tf<<<CDIV(256 * 3456, 256), 256, 0, stream>>>(w5, Wt5, 256, 384, 3, 3, 3456);

    // ---- input to NHWC fp16, C padded to 4
    x_to_nhwc4<<<CDIV(64 * 227 * 227, 256), 256, 0, stream>>>(x, X0);

    // conv1: [64,227,227,4] -> [64,55,55,96]  (KRUN=48, K=528, KP=544)
    conv_mfma<4,227,227,96,11,11,0,4,55,55,48,128,128>
        <<<dim3(CDIV(64 * 55 * 55, 128), 1), 256, 0, stream>>>(X0, Wt1, b1, A);
    {
        const int total8 = 64 * 27 * 27 * (96 / 8);
        avgpool_nhwc8<<<CDIV(total8, 256), 256, 0, stream>>>(A, Bp, 96 / 8, 96, 55, 55, 27, 27, total8);
    }
    // conv2: [64,27,27,96] -> [64,27,27,256]
    conv_mfma<96,27,27,256,5,5,2,1,27,27,0,128,128>
        <<<dim3(CDIV(64 * 27 * 27, 128), 2), 256, 0, stream>>>(Bp, Wt2, b2, A);
    {
        const int total8 = 64 * 13 * 13 * (256 / 8);
        avgpool_nhwc8<<<CDIV(total8, 256), 256, 0, stream>>>(A, Bp, 256 / 8, 256, 27, 27, 13, 13, total8);
    }
    // conv3..5: BM=128 x BN=64 (N=10816 -> 169 n-blocks)
    conv_mfma<256,13,13,384,3,3,1,1,13,13,0,128,64>
        <<<dim3(169, 3), 256, 0, stream>>>(Bp, Wt3, b3, A);
    conv_mfma<384,13,13,384,3,3,1,1,13,13,0,128,64>
        <<<dim3(169, 3), 256, 0, stream>>>(A, Wt4, b4, Bp);
    conv_mfma<384,13,13,256,3,3,1,1,13,13,0,128,64>
        <<<dim3(169, 2), 256, 0, stream>>>(Bp, Wt5, b5, A);

    // pool5 -> Xh1 [64][9216] f16
    pool5_ncflat<<<CDIV(64 * 6 * 6 * 256, 256), 256, 0, stream>>>(A, Xh1);

    // ---- FC stack: split-K partials + reduce (no atomics)
    fc_mfma2<false><<<dim3(16, 16), 256, 0, stream>>>(Xh1, fw1, P, 4096, 4096, 9216, 576);
    fc_reduce<true><<<CDIV(64 * 4096 / 4, 256), 256, 0, stream>>>(P, fb1, Xh2, nullptr, 4096, 4096, 16);
    fc_mfma2<false><<<dim3(16, 16), 256, 0, stream>>>(Xh2, fw2, P, 4096, 4096, 4096, 256);
    fc_reduce<true><<<CDIV(64 * 4096 / 4, 256), 256, 0, stream>>>(P, fb2, Xh3, nullptr, 4096, 4096, 16);
    fc_mfma2<true><<<dim3(4, 64), 256, 0, stream>>>(Xh3, fw3, P, 1000, 1024, 4096, 64);
    fc_reduce<false><<<CDIV(64 * 1000 / 4, 256), 256, 0, stream>>>(P, fb3, nullptr, out, 1000, 1024, 64);
}

// Round 5
// 679.017 us; speedup vs baseline: 1.5165x; 1.0047x over previous
//
#include <hip/hip_runtime.h>

// ============================================================================
// PolyAlexNet forward (round 9).
//   Post-mortem r8: VALU hoist worked (31->20%) but conv2 time unchanged ->
//   VALU was slack, not critical path. MfmaUtil+VALUBusy ~= 48% -> >50% of
//   cycles are stalls: single-LDS-buffer loop with 2 barriers/chunk gives
//   prefetch loads only the ~300cy compute phase in flight vs 200-900cy
//   L2/L3/HBM latency, at only 2-3 blocks/CU (grid-limited).
//   Round-9 change (scheduling only; addresses/masks/traffic identical):
//   LDS DOUBLE-BUFFER in conv_mfma and fc_mfma2:
//     per chunk: frag ds_reads from buf[cur]; ds_write prefetched chunk+1
//     into buf[cur^1]; issue global loads for chunk+2; MFMA; ONE barrier.
//     Loads get a full chunk in flight; barrier count halves; ds_write
//     drain hides under MFMAs. LDS 16->32KB (conv), 20->40KB (FC).
//   Everything else identical to round 8 (682.2 us verified).
// ============================================================================

typedef _Float16 f16;
typedef _Float16 f16x8 __attribute__((ext_vector_type(8)));
typedef float    f32x4 __attribute__((ext_vector_type(4)));

#define CDIV(a,b) (((a)+(b)-1)/(b))
// LDS swizzle: 16B unit g of row stored at slot g ^ ((row>>2)&3)
#define SWZ(row,g) ((g) ^ (((row) >> 2) & 3))

// ---------------------------------------------------------------- conv+poly
// D = A*B: A = weights [OC x K], B = im2col [K x N], N = 64*OH*OW pixels.
// mfma_f32_16x16x32_f16: A/B-frag row = lane&15, k = (lane>>4)*8+j
//                        C/D col(n) = lane&15, row(m) = (lane>>4)*4+reg
// KRUN == 0: vector path, C % 32 == 0 (a chunk has fixed (r,s)).
// KRUN  > 0: conv1 path, per-r run padded to KRUN f16; C = padded channels.
template<int C,int H,int W,int OC,int R,int S,int PAD,int STRIDE,int OH,int OW,
         int KRUN,int BM,int BN>
__global__ __launch_bounds__(256)
void conv_mfma(const f16* __restrict__ in, const f16* __restrict__ wt,
               const float* __restrict__ bias, f16* __restrict__ out)
{
    constexpr int KTOT = (KRUN > 0) ? (R * KRUN) : (C * R * S);
    constexpr int KP   = (KTOT + 31) & ~31;
    constexpr int NC   = KP / 32;
    static_assert(KRUN > 0 || (C % 32) == 0, "vector path requires C % 32 == 0");
    static_assert(NC >= 2, "double-buffer loop assumes >= 2 chunks");
    constexpr int OHW  = OH * OW;
    constexpr int NTOT = 64 * OHW;
    constexpr int AM   = BM / 32;          // m-subtiles per wave (wave = BM/2 x BN/2)
    constexpr int AN   = BN / 32;
    constexpr int AU   = BM * 4 / 256;     // 16B staging units per thread (A)
    constexpr int BU   = BN * 4 / 256;     // 16B staging units per thread (B)

    __shared__ __align__(16) f16 As[2][BM * 32];
    __shared__ __align__(16) f16 Bs[2][BN * 32];

    const int t   = threadIdx.x;
    const int n0  = blockIdx.x * BN;
    const int oc0 = blockIdx.y * BM;

    // ---- A staging metadata (masked loads; clamped pointer base)
    int a_lds[AU]; bool a_ok[AU]; const f16* aptr[AU];
    #pragma unroll
    for (int i = 0; i < AU; ++i) {
        const int u   = t + i * 256;
        const int row = u >> 2;
        const int g   = u & 3;
        a_lds[i] = row * 32 + SWZ(row, g) * 8;
        a_ok[i]  = (oc0 + row) < OC;
        const int rowc = a_ok[i] ? (oc0 + row) : 0;
        aptr[i] = wt + (size_t)rowc * KP + g * 8;
    }
    // ---- B staging metadata (pixel decompose once)
    int b_lds[BU], b_g[BU], b_img[BU], b_oy[BU], b_ox[BU]; bool b_ok[BU];
    #pragma unroll
    for (int i = 0; i < BU; ++i) {
        const int u   = t + i * 256;
        const int row = u >> 2;
        b_g[i]   = u & 3;
        b_lds[i] = row * 32 + SWZ(row, b_g[i]) * 8;
        const int n   = n0 + row;
        b_ok[i]       = n < NTOT;
        const int ncl = b_ok[i] ? n : 0;
        b_img[i] = ncl / OHW;
        const int rem = ncl - b_img[i] * OHW;
        b_oy[i]  = rem / OW;
        b_ox[i]  = rem - b_oy[i] * OW;
    }

    // ---- wave / lane ids
    const int wv = t >> 6;
    const int wm = (wv >> 1) * (BM / 2);
    const int wn = (wv & 1) * (BN / 2);
    const int l  = t & 63;
    const int il = l & 15;
    const int q  = l >> 4;

    f32x4 acc[AM][AN];
    #pragma unroll
    for (int i = 0; i < AM; ++i)
        #pragma unroll
        for (int j = 0; j < AN; ++j)
            acc[i][j] = (f32x4){0.f, 0.f, 0.f, 0.f};

    int4 aReg[AU], bReg[BU];

    auto loadA = [&](int kc) {
        #pragma unroll
        for (int i = 0; i < AU; ++i) {
            int4 v = {0, 0, 0, 0};
            if (a_ok[i]) v = *(const int4*)(aptr[i] + kc);
            aReg[i] = v;
        }
    };

    // ---- vector path: per-(r,s) hoisted state (round-8)
    const f16* bcur[BU]; bool bval[BU];
    auto setRS = [&](int r, int s) {
        if constexpr (KRUN == 0) {
            #pragma unroll
            for (int i = 0; i < BU; ++i) {
                const int iy = b_oy[i] * STRIDE + r - PAD;
                const int ix = b_ox[i] * STRIDE + s - PAD;
                bval[i] = b_ok[i] && iy >= 0 && iy < H && ix >= 0 && ix < W;
                bcur[i] = in + ((size_t)(b_img[i] * H + iy) * W + ix) * C + b_g[i] * 8;
            }
        }
    };
    auto loadBv = [&](int ccoff) {
        #pragma unroll
        for (int i = 0; i < BU; ++i) {
            int4 v = {0, 0, 0, 0};
            if (bval[i]) v = *(const int4*)(bcur[i] + ccoff);
            bReg[i] = v;
        }
    };
    int rn = 0, sn = 0, ccn = 0;   // wave-uniform tap state of last-loaded chunk
    auto advanceB = [&]() {        // advance one chunk and load it
        if constexpr (KRUN == 0) {
            ccn += 32;
            if (ccn == C) {
                ccn = 0;
                if (++sn == S) { sn = 0; ++rn; }
                setRS(rn, sn);
            }
            loadBv(ccn);
        }
    };
    // ---- conv1 KRUN path: per-r runs padded to KRUN, pad 0 (stateless)
    auto loadB1 = [&](int kc) {
        if constexpr (KRUN > 0) {
            #pragma unroll
            for (int i = 0; i < BU; ++i) {
                const int k8 = kc + b_g[i] * 8;
                const int r  = k8 / KRUN;
                const int j0 = k8 - r * KRUN;
                int4 v = {0, 0, 0, 0};
                if (b_ok[i] && k8 < KTOT) {
                    const f16* p = in + ((size_t)(b_img[i] * H + b_oy[i] * STRIDE + r) * W
                                         + b_ox[i] * STRIDE) * C + j0;
                    const int2 lo = *(const int2*)p;
                    const int2 hi = *(const int2*)(p + 4);
                    v.x = lo.x; v.y = lo.y; v.z = hi.x; v.w = hi.y;
                }
                bReg[i] = v;
            }
        }
    };

    auto stage = [&](int nb) {
        #pragma unroll
        for (int i = 0; i < AU; ++i) *(int4*)&As[nb][a_lds[i]] = aReg[i];
        #pragma unroll
        for (int i = 0; i < BU; ++i) *(int4*)&Bs[nb][b_lds[i]] = bReg[i];
    };

    // ---- prologue: chunk 0 -> buf0; chunk 1 -> regs (in flight)
    loadA(0);
    if constexpr (KRUN > 0) loadB1(0); else { setRS(0, 0); loadBv(0); }
    stage(0);
    loadA(32);
    if constexpr (KRUN > 0) loadB1(32); else advanceB();
    __syncthreads();

    // ---- main loop: one barrier per chunk
    for (int ci = 0; ci < NC; ++ci) {
        const int cb = ci & 1;

        f16x8 af[AM], bf[AN];
        #pragma unroll
        for (int mi = 0; mi < AM; ++mi) {
            const int row = wm + mi * 16 + il;
            af[mi] = *(const f16x8*)&As[cb][row * 32 + SWZ(row, q) * 8];
        }
        #pragma unroll
        for (int ni = 0; ni < AN; ++ni) {
            const int row = wn + ni * 16 + il;
            bf[ni] = *(const f16x8*)&Bs[cb][row * 32 + SWZ(row, q) * 8];
        }

        if (ci + 1 < NC) {
            stage(cb ^ 1);                       // regs = chunk ci+1 (vm-wait here)
            if (ci + 2 < NC) {                   // issue chunk ci+2 loads
                loadA((ci + 2) * 32);
                if constexpr (KRUN > 0) loadB1((ci + 2) * 32); else advanceB();
            }
        }

        #pragma unroll
        for (int mi = 0; mi < AM; ++mi)
            #pragma unroll
            for (int ni = 0; ni < AN; ++ni)
                acc[mi][ni] = __builtin_amdgcn_mfma_f32_16x16x32_f16(
                    af[mi], bf[ni], acc[mi][ni], 0, 0, 0);

        if (ci + 1 < NC) __syncthreads();
    }

    // ---- poly epilogue: out[n][oc] = (acc + bias[oc] + 1)^2, NHWC fp16
    #pragma unroll
    for (int mi = 0; mi < AM; ++mi) {
        const int ocb = oc0 + wm + mi * 16 + q * 4;
        if (ocb >= OC) continue;
        const float4 bb = *(const float4*)(bias + ocb);
        const float b4[4] = {bb.x + 1.f, bb.y + 1.f, bb.z + 1.f, bb.w + 1.f};
        #pragma unroll
        for (int ni = 0; ni < AN; ++ni) {
            const int nn = n0 + wn + ni * 16 + il;
            if (nn >= NTOT) continue;
            const f32x4 v = acc[mi][ni];
            union { f16 h[4]; uint2 u; } cv;
            const float vv[4] = {v.x, v.y, v.z, v.w};
            #pragma unroll
            for (int rr = 0; rr < 4; ++rr) {
                const float y = vv[rr] + b4[rr];
                cv.h[rr] = (f16)(y * y);
            }
            *(uint2*)(out + (size_t)nn * OC + ocb) = cv.u;
        }
    }
}

// ---------------------------------------------------------------- FC GEMM
// P[s][64][Npad] (fp32) = X[64][k-slab] @ W[k-slab][n-tile]
template<bool TAIL>
__global__ __launch_bounds__(256)
void fc_mfma2(const f16* __restrict__ X, const float* __restrict__ Wm,
              float* __restrict__ P, int N, int Npad, int K, int kchunk)
{
    __shared__ __align__(16) f16 Xs[2][64 * 32];    // 8 KB
    __shared__ __align__(16) f16 Ws[2][256 * 32];   // 32 KB

    const int t  = threadIdx.x;
    const int n0 = blockIdx.x * 256;
    const int s  = blockIdx.y;
    const int k0 = s * kchunk;
    const int nIter = kchunk / 32;

    const bool wok = !TAIL || (n0 + t) < N;
    const float* __restrict__ wbase = Wm + (size_t)k0 * N + n0 + t;
    const int xm = t >> 2;
    const int xg = t & 3;
    const f16* __restrict__ xbase = X + (size_t)xm * K + k0 + xg * 8;
    const int xoff = xm * 32 + SWZ(xm, xg) * 8;

    const int wq = t >> 6;
    const int l  = t & 63;
    const int il = l & 15;
    const int q  = l >> 4;

    f32x4 acc[4][4];
    #pragma unroll
    for (int i = 0; i < 4; ++i)
        #pragma unroll
        for (int j = 0; j < 4; ++j)
            acc[i][j] = (f32x4){0.f, 0.f, 0.f, 0.f};

    float wreg[4][8];
    int4  xreg;

    auto loadChunk = [&](int it) {
        const size_t kbase = (size_t)it * 32;
        #pragma unroll
        for (int g = 0; g < 4; ++g)
            #pragma unroll
            for (int j = 0; j < 8; ++j)
                wreg[g][j] = wok ? wbase[(kbase + g * 8 + j) * N] : 0.f;
        xreg = *(const int4*)(xbase + kbase);
    };

    auto stage = [&](int nb) {
        #pragma unroll
        for (int g = 0; g < 4; ++g) {
            f16x8 h;
            #pragma unroll
            for (int j = 0; j < 8; ++j) h[j] = (f16)wreg[g][j];
            *(f16x8*)&Ws[nb][t * 32 + SWZ(t, g) * 8] = h;
        }
        *(int4*)&Xs[nb][xoff] = xreg;
    };

    // ---- prologue: chunk 0 -> buf0; chunk 1 -> regs (in flight)
    loadChunk(0);
    stage(0);
    if (nIter > 1) loadChunk(1);
    __syncthreads();

    for (int it = 0; it < nIter; ++it) {
        const int cb = it & 1;

        f16x8 af[4], bf[4];
        #pragma unroll
        for (int mi = 0; mi < 4; ++mi) {
            const int m = mi * 16 + il;
            af[mi] = *(const f16x8*)&Xs[cb][m * 32 + SWZ(m, q) * 8];
        }
        #pragma unroll
        for (int ni = 0; ni < 4; ++ni) {
            const int n = wq * 64 + ni * 16 + il;
            bf[ni] = *(const f16x8*)&Ws[cb][n * 32 + SWZ(n, q) * 8];
        }

        if (it + 1 < nIter) {
            stage(cb ^ 1);                        // regs = chunk it+1
            if (it + 2 < nIter) loadChunk(it + 2);
        }

        #pragma unroll
        for (int mi = 0; mi < 4; ++mi)
            #pragma unroll
            for (int ni = 0; ni < 4; ++ni)
                acc[mi][ni] = __builtin_amdgcn_mfma_f32_16x16x32_f16(
                    af[mi], bf[ni], acc[mi][ni], 0, 0, 0);

        if (it + 1 < nIter) __syncthreads();
    }

    float* __restrict__ pb = P + (size_t)s * 64 * Npad + n0;
    #pragma unroll
    for (int mi = 0; mi < 4; ++mi) {
        const int m = mi * 16 + q * 4;
        #pragma unroll
        for (int ni = 0; ni < 4; ++ni) {
            const int n = wq * 64 + ni * 16 + il;
            const f32x4 v = acc[mi][ni];
            const float vv[4] = {v.x, v.y, v.z, v.w};
            #pragma unroll
            for (int rr = 0; rr < 4; ++rr)
                pb[(size_t)(m + rr) * Npad + n] = vv[rr];
        }
    }
}

// reduce: out[m][n] = bias[n] + sum_s P[s][m][n]
template<bool F16OUT>
__global__ __launch_bounds__(256)
void fc_reduce(const float* __restrict__ P, const float* __restrict__ bias,
               f16* __restrict__ o16, float* __restrict__ o32,
               int N, int Npad, int S)
{
    const int idx = blockIdx.x * 256 + threadIdx.x;
    const int total = 64 * (N / 4);
    if (idx >= total) return;
    const int n4 = (idx % (N / 4)) * 4;
    const int m  = idx / (N / 4);
    float4 a = *(const float4*)(bias + n4);
    const float* __restrict__ p = P + (size_t)m * Npad + n4;
    for (int s = 0; s < S; ++s) {
        const float4 v = *(const float4*)(p + (size_t)s * 64 * Npad);
        a.x += v.x; a.y += v.y; a.z += v.z; a.w += v.w;
    }
    if (F16OUT) {
        union { f16 h[4]; uint2 u; } cv;
        cv.h[0] = (f16)a.x; cv.h[1] = (f16)a.y;
        cv.h[2] = (f16)a.z; cv.h[3] = (f16)a.w;
        *(uint2*)(o16 + (size_t)m * N + n4) = cv.u;
    } else {
        *(float4*)(o32 + (size_t)m * N + n4) = a;
    }
}

// ---------------------------------------------------------------- NHWC avgpool
// 8 channels per thread (16B/lane loads+stores)
__global__ __launch_bounds__(256)
void avgpool_nhwc8(const f16* __restrict__ in, f16* __restrict__ out,
                   int C8, int C, int H, int W, int OH, int OW, int total8)
{
    const int idx = blockIdx.x * 256 + threadIdx.x;
    if (idx >= total8) return;
    const int c8  = (idx % C8) * 8;
    int rest      = idx / C8;
    const int ox  = rest % OW; rest /= OW;
    const int oy  = rest % OH;
    const int b   = rest / OH;
    const f16* __restrict__ p = in + ((size_t)(b * H + oy * 2) * W + ox * 2) * C + c8;
    float s[8] = {0.f, 0.f, 0.f, 0.f, 0.f, 0.f, 0.f, 0.f};
    #pragma unroll
    for (int r = 0; r < 3; ++r)
        #pragma unroll
        for (int cc = 0; cc < 3; ++cc) {
            const f16x8 v = *(const f16x8*)&p[(r * W + cc) * C];
            #pragma unroll
            for (int j = 0; j < 8; ++j) s[j] += (float)v[j];
        }
    f16x8 o8;
    #pragma unroll
    for (int j = 0; j < 8; ++j) o8[j] = (f16)(s[j] * (1.f / 9.f));
    *(f16x8*)(out + (size_t)idx * 8) = o8;
}

// pool5: NHWC fp16 [64][13][13][256] -> fp16 [64][9216] NCHW-flat
__global__ __launch_bounds__(256)
void pool5_ncflat(const f16* __restrict__ in, f16* __restrict__ out)
{
    const int idx = blockIdx.x * 256 + threadIdx.x;
    if (idx >= 64 * 6 * 6 * 256) return;
    const int c  = idx & 255;
    int rest     = idx >> 8;
    const int ox = rest % 6; rest /= 6;
    const int oy = rest % 6;
    const int b  = rest / 6;
    const f16* __restrict__ p = in + ((size_t)(b * 13 + oy * 2) * 13 + ox * 2) * 256 + c;
    float s = 0.f;
    #pragma unroll
    for (int r = 0; r < 3; ++r)
        #pragma unroll
        for (int cc = 0; cc < 3; ++cc)
            s += (float)p[(r * 13 + cc) * 256];
    out[(size_t)b * 9216 + c * 36 + oy * 6 + ox] = (f16)(s * (1.f / 9.f));
}

// ---------------------------------------------------------------- transforms
// input NCHW fp32 -> NHWC fp16, channels padded 3 -> 4 (pixel = 8B aligned)
__global__ __launch_bounds__(256)
void x_to_nhwc4(const float* __restrict__ x, f16* __restrict__ o)
{
    const int idx = blockIdx.x * 256 + threadIdx.x;
    if (idx >= 64 * 227 * 227) return;
    const int hw = idx % (227 * 227);
    const int b  = idx / (227 * 227);
    const size_t plane = 227 * 227;
    const float* __restrict__ p = x + (size_t)b * 3 * plane + hw;
    union { f16 h[4]; int2 v; } u;
    u.h[0] = (f16)p[0];
    u.h[1] = (f16)p[plane];
    u.h[2] = (f16)p[2 * plane];
    u.h[3] = (f16)0.f;
    *(int2*)(o + (size_t)idx * 4) = u.v;
}

// conv1 weights OIHW fp32 -> [96][r*48 + s*4 + c] fp16, zero-padded (KP=544)
__global__ __launch_bounds__(256)
void wt_tf1(const float* __restrict__ w, f16* __restrict__ o)
{
    const int idx = blockIdx.x * 256 + threadIdx.x;
    if (idx >= 96 * 544) return;
    const int k  = idx % 544;
    const int oc = idx / 544;
    f16 v = (f16)0.f;
    if (k < 528) {
        const int r   = k / 48;
        const int rem = k - r * 48;
        const int s   = rem >> 2;
        const int c   = rem & 3;
        if (s < 11 && c < 3)
            v = (f16)w[(((size_t)oc * 3 + c) * 11 + r) * 11 + s];
    }
    o[idx] = v;
}

// weights OIHW fp32 -> [OC][(r*S+s)*C + c] fp16, K zero-padded to KP
__global__ __launch_bounds__(256)
void wt_tf(const float* __restrict__ w, f16* __restrict__ o,
           int OC, int Cc, int R, int S, int KP)
{
    const int idx = blockIdx.x * 256 + threadIdx.x;
    if (idx >= OC * KP) return;
    const int k  = idx % KP;
    const int oc = idx / KP;
    f16 v = (f16)0.f;
    if (k < Cc * R * S) {
        const int rs = k / Cc;
        const int c  = k - rs * Cc;
        const int r  = rs / S;
        const int s  = rs - r * S;
        v = (f16)w[(((size_t)oc * Cc + c) * R + r) * S + s];
    }
    o[idx] = v;
}

// ============================================================================
extern "C" void kernel_launch(void* const* d_in, const int* in_sizes, int n_in,
                              void* d_out, int out_size, void* d_ws, size_t ws_size,
                              hipStream_t stream)
{
    const float* x   = (const float*)d_in[0];
    const float* w1  = (const float*)d_in[1];
    const float* b1  = (const float*)d_in[2];
    const float* w2  = (const float*)d_in[3];
    const float* b2  = (const float*)d_in[4];
    const float* w3  = (const float*)d_in[5];
    const float* b3  = (const float*)d_in[6];
    const float* w4  = (const float*)d_in[7];
    const float* b4  = (const float*)d_in[8];
    const float* w5  = (const float*)d_in[9];
    const float* b5  = (const float*)d_in[10];
    const float* fw1 = (const float*)d_in[11];
    const float* fb1 = (const float*)d_in[12];
    const float* fw2 = (const float*)d_in[13];
    const float* fb2 = (const float*)d_in[14];
    const float* fw3 = (const float*)d_in[15];
    const float* fb3 = (const float*)d_in[16];
    float* out = (float*)d_out;

    char* ws = (char*)d_ws;
    const size_t MiB = 1024 * 1024;

    // ws map (round-6, verified):
    //   [0, 26MiB)    X0 (conv1 input, C4-padded NHWC, 25.2MB; dead after conv1)
    //   [0, 17MiB)    P  (FC partials, <=16.8MB; FC stage only -> overlaps X0)
    //   [17, 21MiB)   Xh1/Xh2/Xh3
    //   [26, 62MiB)   A  (<=37.2MB)
    //   [62, 72MiB)   Bp (<=9.0MB)
    //   [72, 80MiB)   packed conv weights (~7.5MB)
    f16*   X0  = (f16*)(ws);
    float* P   = (float*)(ws);
    f16*   Xh1 = (f16*)(ws + 17 * MiB);
    f16*   Xh2 = (f16*)(ws + 19 * MiB);
    f16*   Xh3 = (f16*)(ws + 20 * MiB);
    f16*   A   = (f16*)(ws + 26 * MiB);
    f16*   Bp  = (f16*)(ws + 62 * MiB);
    f16*   Wt1 = (f16*)(ws + 72 * MiB);
    f16*   Wt2 = Wt1 + (size_t)96  * 544;
    f16*   Wt3 = Wt2 + (size_t)256 * 2400;
    f16*   Wt4 = Wt3 + (size_t)384 * 2304;
    f16*   Wt5 = Wt4 + (size_t)384 * 3456;

    // ---- conv weight transforms (tiny)
    wt_tf1<<<CDIV(96 * 544, 256), 256, 0, stream>>>(w1, Wt1);
    wt_tf<<<CDIV(256 * 2400, 256), 256, 0, stream>>>(w2, Wt2, 256, 96 , 5, 5, 2400);
    wt_tf<<<CDIV(384 * 2304, 256), 256, 0, stream>>>(w3, Wt3, 384, 256, 3, 3, 2304);
    wt_tf<<<CDIV(384 * 3456, 256), 256, 0, stream>>>(w4, Wt4, 384, 384, 3, 3, 3456);
    wt_tf<<<CDIV(256 * 3456, 256), 256, 0, stream>>>(w5, Wt5, 256, 384, 3, 3, 3456);

    // ---- input to NHWC fp16, C padded to 4
    x_to_nhwc4<<<CDIV(64 * 227 * 227, 256), 256, 0, stream>>>(x, X0);

    // conv1: [64,227,227,4] -> [64,55,55,96]  (KRUN=48, K=528, KP=544)
    conv_mfma<4,227,227,96,11,11,0,4,55,55,48,128,128>
        <<<dim3(CDIV(64 * 55 * 55, 128), 1), 256, 0, stream>>>(X0, Wt1, b1, A);
    {
        const int total8 = 64 * 27 * 27 * (96 / 8);
        avgpool_nhwc8<<<CDIV(total8, 256), 256, 0, stream>>>(A, Bp, 96 / 8, 96, 55, 55, 27, 27, total8);
    }
    // conv2: [64,27,27,96] -> [64,27,27,256]
    conv_mfma<96,27,27,256,5,5,2,1,27,27,0,128,128>
        <<<dim3(CDIV(64 * 27 * 27, 128), 2), 256, 0, stream>>>(Bp, Wt2, b2, A);
    {
        const int total8 = 64 * 13 * 13 * (256 / 8);
        avgpool_nhwc8<<<CDIV(total8, 256), 256, 0, stream>>>(A, Bp, 256 / 8, 256, 27, 27, 13, 13, total8);
    }
    // conv3..5: BM=128 x BN=64 (N=10816 -> 169 n-blocks)
    conv_mfma<256,13,13,384,3,3,1,1,13,13,0,128,64>
        <<<dim3(169, 3), 256, 0, stream>>>(Bp, Wt3, b3, A);
    conv_mfma<384,13,13,384,3,3,1,1,13,13,0,128,64>
        <<<dim3(169, 3), 256, 0, stream>>>(A, Wt4, b4, Bp);
    conv_mfma<384,13,13,256,3,3,1,1,13,13,0,128,64>
        <<<dim3(169, 2), 256, 0, stream>>>(Bp, Wt5, b5, A);

    // pool5 -> Xh1 [64][9216] f16
    pool5_ncflat<<<CDIV(64 * 6 * 6 * 256, 256), 256, 0, stream>>>(A, Xh1);

    // ---- FC stack: split-K partials + reduce (no atomics)
    fc_mfma2<false><<<dim3(16, 16), 256, 0, stream>>>(Xh1, fw1, P, 4096, 4096, 9216, 576);
    fc_reduce<true><<<CDIV(64 * 4096 / 4, 256), 256, 0, stream>>>(P, fb1, Xh2, nullptr, 4096, 4096, 16);
    fc_mfma2<false><<<dim3(16, 16), 256, 0, stream>>>(Xh2, fw2, P, 4096, 4096, 4096, 256);
    fc_reduce<true><<<CDIV(64 * 4096 / 4, 256), 256, 0, stream>>>(P, fb2, Xh3, nullptr, 4096, 4096, 16);
    fc_mfma2<true><<<dim3(4, 64), 256, 0, stream>>>(Xh3, fw3, P, 1000, 1024, 4096, 64);
    fc_reduce<false><<<CDIV(64 * 1000 / 4, 256), 256, 0, stream>>>(P, fb3, nullptr, out, 1000, 1024, 64);
}